// Round 10
// baseline (378.647 us; speedup 1.0000x reference)
//
#include <hip/hip_runtime.h>
#include <stdint.h>
#include <stddef.h>

// ==== JAX threefry mode: 1 = jax_threefry_partitionable (default in modern JAX)
#define JAX_PARTITIONABLE 1

#define B_   256
#define N_   512
#define NP_  513     // N+1
#define KROW 516     // padded key row stride (floats)
#define T_   64
#define CS   4       // sampling chunk size (steps)
#define NCH  16      // T_/CS
#define NEGC 1e9f

// ---------------- threefry2x32 (matches jax/_src/prng.py) ----------------
__host__ __device__ __forceinline__ void tf2x32(uint32_t k0, uint32_t k1,
    uint32_t x0, uint32_t x1, uint32_t& o0, uint32_t& o1) {
  const uint32_t k2 = k0 ^ k1 ^ 0x1BD11BDAu;
#define TFR(r) { x0 += x1; x1 = (x1 << (r)) | (x1 >> (32 - (r))); x1 ^= x0; }
  x0 += k0; x1 += k1;
  TFR(13) TFR(15) TFR(26) TFR(6)
  x0 += k1; x1 += k2 + 1u;
  TFR(17) TFR(29) TFR(16) TFR(24)
  x0 += k2; x1 += k0 + 2u;
  TFR(13) TFR(15) TFR(26) TFR(6)
  x0 += k0; x1 += k1 + 3u;
  TFR(17) TFR(29) TFR(16) TFR(24)
  x0 += k1; x1 += k2 + 4u;
  TFR(13) TFR(15) TFR(26) TFR(6)
  x0 += k2; x1 += k0 + 5u;
#undef TFR
  o0 = x0; o1 = x1;
}

struct SkKeys { uint32_t k[128]; };

static SkKeys compute_chain() {
  SkKeys s;
  uint32_t r0 = 0u, r1 = 42u;   // jax.random.key(42)
  for (int t = 0; t < 64; ++t) {
#if JAX_PARTITIONABLE
    uint32_t a0, a1, b0, b1;
    tf2x32(r0, r1, 0u, 0u, a0, a1);
    tf2x32(r0, r1, 0u, 1u, b0, b1);
    s.k[2*t] = b0; s.k[2*t+1] = b1;
    r0 = a0; r1 = a1;
#else
    uint32_t p0, p1, q0, q1;
    tf2x32(r0, r1, 0u, 2u, p0, p1);
    tf2x32(r0, r1, 1u, 3u, q0, q1);
    s.k[2*t] = p1; s.k[2*t+1] = q1;
    r0 = p0; r1 = q0;
#endif
  }
  return s;
}

__device__ __forceinline__ float gumbel_draw(uint32_t k0, uint32_t k1, int b, int n) {
  uint32_t bits;
#if JAX_PARTITIONABLE
  uint32_t j = (uint32_t)(b * NP_ + n);
  uint32_t o0, o1; tf2x32(k0, k1, 0u, j, o0, o1);
  bits = o0 ^ o1;
#else
  int j = b * NP_ + n;
  uint32_t o0, o1;
  if (j < 65664) { tf2x32(k0, k1, (uint32_t)j, (uint32_t)(j + 65664), o0, o1); bits = o0; }
  else           { tf2x32(k0, k1, (uint32_t)(j - 65664), (uint32_t)j, o0, o1); bits = o1; }
#endif
  float f = __uint_as_float((bits >> 9) | 0x3F800000u) - 1.0f;
  const float TINY = 1.17549435e-38f;
  float u = fmaxf(TINY, f + TINY);
  return -logf(-logf(u));
}

__device__ __forceinline__ float sigm(float x) {
  return 0.5f + 0.5f * tanhf(0.5f * x);   // XLA logistic
}

// barrier with LDS-only drain (no vmcnt: global stores never read back)
__device__ __forceinline__ void bar_lds() {
  asm volatile("s_waitcnt lgkmcnt(0)\n\ts_barrier" ::: "memory");
}
__device__ __forceinline__ void lds_fence() {
  asm volatile("s_waitcnt lgkmcnt(0)" ::: "memory");
}

// ---------------- LDS layout (floats) ----------------
#define OFF_KEY   0        // 32*516 = 16512, c-major [32][516]
#define OFF_H     16512    // 64*32 = 2048
#define OFF_WB    18560    // 8192: wx[32][128] | wh[32][128] (k-major, conflict-free)
#define OFF_Q     26752    // 2 slots * 2064 = 4128
#define OFF_G     30880    // 3 slots * 2064 = 6192
#define OFF_UNITS 37072    // 516
#define OFF_SK    37588    // 128 (u32 aliased)
#define OFF_ES    37716    // 32
#define OFF_PART  37748    // 512
#define OFF_T     38260    // 256
#define OFF_X0    38516    // 32
#define LDS_FLOATS 38548   // 154,192 B

__global__ void __launch_bounds__(512, 2)
suh_fused(const float* __restrict__ emb, const float* __restrict__ autm,
          const float* __restrict__ aum, const float* __restrict__ ent,
          const float* __restrict__ temp_p,
          const float* __restrict__ key_w, const float* __restrict__ key_b,
          const float* __restrict__ func_w, const float* __restrict__ func_b,
          const float* __restrict__ fc1_w, const float* __restrict__ fc1_b,
          const float* __restrict__ fc2_w, const float* __restrict__ fc2_b,
          const float* __restrict__ emb_w, const float* __restrict__ emb_b,
          const float* __restrict__ wx, const float* __restrict__ wh,
          const float* __restrict__ lstm_bb,
          const float* __restrict__ ln_gx, const float* __restrict__ ln_bx,
          const float* __restrict__ ln_gh, const float* __restrict__ ln_bh,
          float* __restrict__ out_logits, float* __restrict__ out_valid,
          float* __restrict__ out_units, float* __restrict__ out_final,
          SkKeys sk)
{
  extern __shared__ __align__(16) float sm[];
  int* smi = (int*)sm;
  const int b   = blockIdx.x;
  const int tid = threadIdx.x;
  const int L   = tid - 64;         // worker lane id (valid for tid >= 64)

  const float temp = temp_p[0];

  // ======== init: weights->LDS, sk->LDS, zero key row ========
  {
    const float4* wx4 = (const float4*)wx;
    const float4* wh4 = (const float4*)wh;
    float4* wb4 = (float4*)(sm + OFF_WB);
    for (int i = tid; i < 1024; i += 512) wb4[i] = wx4[i];
    for (int i = tid; i < 1024; i += 512) wb4[1024 + i] = wh4[i];
    if (tid < 128) smi[OFF_SK + tid] = (int)sk.k[tid];
    if (tid >= 480) sm[OFF_KEY + (tid - 480) * KROW + N_] = 0.f;  // zero key row
  }
  __syncthreads();

  // ======== P0: T = relu(emb@fc1+b1) + relu(autm@func+fb) ========
  if (tid < 256) {
    float a = 0.f;
    const float* e = emb + (size_t)b * 1024;
    #pragma unroll 8
    for (int k = 0; k < 1024; ++k) a += e[k] * fc1_w[k * 256 + tid];
    a = fmaxf(a + fc1_b[tid], 0.f);
    float f = 0.f;
    const float* m = autm + (size_t)b * 259;
    for (int k = 0; k < 259; ++k) f += m[k] * func_w[k * 256 + tid];
    f = fmaxf(f + func_b[tid], 0.f);
    sm[OFF_T + tid] = a + f;
  }
  __syncthreads();

  // ======== P1: x0 = relu(T@fc2 + b2) ========
  if (tid < 32) {
    float s = 0.f;
    #pragma unroll 8
    for (int m2 = 0; m2 < 256; ++m2) s += sm[OFF_T + m2] * fc2_w[m2 * 32 + tid];
    sm[OFF_X0 + tid] = fmaxf(s + fc2_b[tid], 0.f);
  }
  __syncthreads();

  // persistent worker state (key columns in registers)
  float kr0[32], kr1[32];
  // persistent wave0 sampling state
  float mreg[8], ureg[8];
  float m512 = 1.0f;
  int done_reg = 0;

  // prep lambdas (workers, L = 0..447)
  auto qprep = [&](int cc, int qs) {
    const int qb = OFF_Q + qs * (CS * 516);
    #pragma unroll 1
    for (int tl = 0; tl < CS; ++tl) {
      const int hb = OFF_H + (cc * CS + tl) * 32;
      float hv[32];
      #pragma unroll
      for (int r = 0; r < 8; ++r) {
        float4 v = *(const float4*)&sm[hb + r * 4];
        hv[r*4] = v.x; hv[r*4+1] = v.y; hv[r*4+2] = v.z; hv[r*4+3] = v.w;
      }
      float a0 = 0.f;
      #pragma unroll
      for (int k = 0; k < 32; ++k) a0 += hv[k] * kr0[k];
      sm[qb + tl * 516 + L] = a0 * (1.0f / 32.0f);
      if (L < 64) {
        float a1 = 0.f;
        #pragma unroll
        for (int k = 0; k < 32; ++k) a1 += hv[k] * kr1[k];
        sm[qb + tl * 516 + L + 448] = a1 * (1.0f / 32.0f);
      }
    }
  };
  auto gprep = [&](int cc, int gs) {
    const int gb = OFF_G + gs * (CS * 516);
    #pragma unroll 1
    for (int ii = 0; ii < 5; ++ii) {
      const int idx = ii * 448 + L;
      if (idx < CS * 512) {
        const int tl = idx >> 9, n = idx & 511;
        const int t = cc * CS + tl;
        sm[gb + tl * 516 + n] =
            gumbel_draw((uint32_t)smi[OFF_SK + 2*t], (uint32_t)smi[OFF_SK + 2*t + 1], b, n);
      }
    }
    if (L < CS) {
      const int t = cc * CS + L;
      sm[gb + L * 516 + N_] =
          gumbel_draw((uint32_t)smi[OFF_SK + 2*t], (uint32_t)smi[OFF_SK + 2*t + 1], b, N_);
    }
  };

  // ======== P2: wave0 beta (64 LSTM steps, LDS weights) || workers keyGEMM + G prefill ========
  if (tid < 64) {
    const float gxg0 = ln_gx[tid], gxg1 = ln_gx[tid + 64];
    const float gxb0 = ln_bx[tid], gxb1 = ln_bx[tid + 64];
    const float ghg0 = ln_gh[tid], ghg1 = ln_gh[tid + 64];
    const float ghb0 = ln_bh[tid], ghb1 = ln_bh[tid + 64];
    const float lb0  = lstm_bb[tid], lb1 = lstm_bb[tid + 64];

    float xf[32];
    #pragma unroll
    for (int r = 0; r < 8; ++r) {
      float4 v = *(const float4*)&sm[OFF_X0 + r * 4];
      xf[r*4] = v.x; xf[r*4+1] = v.y; xf[r*4+2] = v.z; xf[r*4+3] = v.w;
    }
    float creg = 0.f;

    #pragma unroll 1
    for (int t = 0; t < T_; ++t) {
      float a0 = 0.f, a1 = 0.f, b0 = 0.f, b1 = 0.f;
      #pragma unroll
      for (int k = 0; k < 32; ++k) {
        a0 += xf[k] * sm[OFF_WB + k * 128 + tid];
        a1 += xf[k] * sm[OFF_WB + k * 128 + 64 + tid];
      }
      if (t > 0) {                        // at t==0, h==0 -> gh exactly 0
        #pragma unroll
        for (int k = 0; k < 32; ++k) {
          b0 += xf[k] * sm[OFF_WB + 4096 + k * 128 + tid];
          b1 += xf[k] * sm[OFF_WB + 4096 + k * 128 + 64 + tid];
        }
      }
      float sx = a0 + a1, sh = b0 + b1;
      for (int off = 32; off; off >>= 1) {
        sx += __shfl_down(sx, off);
        sh += __shfl_down(sh, off);
      }
      float mx  = __shfl(sx, 0) * (1.0f / 128.0f);
      float mh2 = __shfl(sh, 0) * (1.0f / 128.0f);
      float dx0 = a0 - mx, dx1 = a1 - mx;
      float dh0 = b0 - mh2, dh1 = b1 - mh2;
      float ssx = dx0 * dx0 + dx1 * dx1;
      float ssh = dh0 * dh0 + dh1 * dh1;
      for (int off = 32; off; off >>= 1) {
        ssx += __shfl_down(ssx, off);
        ssh += __shfl_down(ssh, off);
      }
      float vx = __shfl(ssx, 0) * (1.0f / 128.0f);
      float vh = __shfl(ssh, 0) * (1.0f / 128.0f);
      float rx = 1.0f / sqrtf(vx + 1e-5f);
      float rh = 1.0f / sqrtf(vh + 1e-5f);
      float lnx0 = dx0 * rx * gxg0 + gxb0;
      float lnx1 = dx1 * rx * gxg1 + gxb1;
      float lnh0 = dh0 * rh * ghg0 + ghb0;
      float lnh1 = dh1 * rh * ghg1 + ghb1;
      float g0 = lnx0 + lnh0 + lb0;       // gate[tid]     (i|f half)
      float g1 = lnx1 + lnh1 + lb1;       // gate[tid+64]  (o|u half)
      float fq = __shfl(g0, tid + 32);
      float uq = __shfl(g1, tid + 32);
      float cN = sigm(fq) * creg + sigm(g0) * tanhf(uq);
      float hN = sigm(g1) * tanhf(cN);
      creg = cN;                           // garbage lanes>=32, never read
      if (tid < 32) sm[OFF_H + t * 32 + tid] = hN;
      lds_fence();
      // h broadcast via LDS (8 b128 reads, all lanes same addr = broadcast)
      #pragma unroll
      for (int r = 0; r < 8; ++r) {
        float4 v = *(const float4*)&sm[OFF_H + t * 32 + r * 4];
        xf[r*4] = v.x; xf[r*4+1] = v.y; xf[r*4+2] = v.z; xf[r*4+3] = v.w;
      }
    }
  } else {
    // ---- workers: key GEMM rows L (and L+448 for L<64), ascending-k chains ----
    const float4* kw4 = (const float4*)key_w;
    {
      const float4* er = (const float4*)(ent + ((size_t)b * N_ + L) * 256);
      float acc[32];
      #pragma unroll
      for (int c = 0; c < 32; ++c) acc[c] = 0.f;
      #pragma unroll 4
      for (int k4 = 0; k4 < 64; ++k4) {
        float4 ev = er[k4];
        float e4[4] = {ev.x, ev.y, ev.z, ev.w};
        #pragma unroll
        for (int j = 0; j < 4; ++j) {
          const int k = k4 * 4 + j;
          #pragma unroll
          for (int c4 = 0; c4 < 8; ++c4) {
            float4 w = kw4[k * 8 + c4];          // wave-uniform
            acc[c4*4+0] += e4[j] * w.x;
            acc[c4*4+1] += e4[j] * w.y;
            acc[c4*4+2] += e4[j] * w.z;
            acc[c4*4+3] += e4[j] * w.w;
          }
        }
      }
      #pragma unroll
      for (int c = 0; c < 32; ++c) {
        kr0[c] = acc[c] + key_b[c];
        sm[OFF_KEY + c * KROW + L] = kr0[c];
      }
    }
    if (L < 64) {
      const int n = L + 448;
      const float4* er = (const float4*)(ent + ((size_t)b * N_ + n) * 256);
      float acc[32];
      #pragma unroll
      for (int c = 0; c < 32; ++c) acc[c] = 0.f;
      #pragma unroll 4
      for (int k4 = 0; k4 < 64; ++k4) {
        float4 ev = er[k4];
        float e4[4] = {ev.x, ev.y, ev.z, ev.w};
        #pragma unroll
        for (int j = 0; j < 4; ++j) {
          const int k = k4 * 4 + j;
          #pragma unroll
          for (int c4 = 0; c4 < 8; ++c4) {
            float4 w = kw4[k * 8 + c4];
            acc[c4*4+0] += e4[j] * w.x;
            acc[c4*4+1] += e4[j] * w.y;
            acc[c4*4+2] += e4[j] * w.z;
            acc[c4*4+3] += e4[j] * w.w;
          }
        }
      }
      #pragma unroll
      for (int c = 0; c < 32; ++c) {
        kr1[c] = acc[c] + key_b[c];
        sm[OFF_KEY + c * KROW + n] = kr1[c];
      }
    }
    #pragma unroll
    for (int k = 0; k < 32; ++k) {
      asm volatile("" : "+v"(kr0[k]), "+v"(kr1[k]));
    }
    // gumbel prefill for chunks 0,1 (G ring slots 0,1) — hidden under beta
    gprep(0, 0);
    gprep(1, 1);
  }
  __syncthreads();   // H + key + G[0,1] complete

  // ======== P3 pre-loop: workers prep Q(0); wave0 loads mask state ========
  if (tid < 64) {
    #pragma unroll
    for (int j = 0; j < 8; ++j) {
      mreg[j] = aum[(size_t)b * N_ + tid + 64 * j];
      ureg[j] = 0.f;
    }
  } else {
    qprep(0, 0);
  }
  bar_lds();

  // ======== pipelined sampling: wave0 samples chunk c || workers prep Q(c+1), G(c+2) ========
  for (int c = 0; c < NCH; ++c) {
    if (tid < 64) {
      const int qbase = OFF_Q + (c & 1) * (CS * 516);
      const int gbase = OFF_G + (c % 3) * (CS * 516);
      #pragma unroll 1
      for (int tl = 0; tl < CS; ++tl) {
        const int t = c * CS + tl;
        float* lrow = out_logits + ((size_t)t * B_ + b) * NP_;
        float bv = 0.f; int bi = 0;
        #pragma unroll
        for (int j = 0; j < 8; ++j) {
          const int n = tid + 64 * j;
          float q = sm[qbase + tl * 516 + n] - (1.0f - mreg[j]) * NEGC;
          lrow[n] = q;
          float v = q / temp + sm[gbase + tl * 516 + n];
          if (j == 0) { bv = v; bi = n; }
          else if (v > bv) { bv = v; bi = n; }
        }
        if (tid == 0) {
          float q = -(1.0f - m512) * NEGC;   // zero key row: dot == 0
          lrow[N_] = q;
          float v = q / temp + sm[gbase + tl * 516 + N_];
          if (v > bv) { bv = v; bi = N_; }
        }
        for (int off = 32; off; off >>= 1) {
          float ov = __shfl_down(bv, off);
          int   oi = __shfl_down(bi, off);
          if (ov > bv || (ov == bv && oi < bi)) { bv = ov; bi = oi; }
        }
        const int sel_i = __shfl(bi, 0);
        const int active = !done_reg;
        const int is_end = (sel_i == N_);
        if (tid == 0) out_valid[(size_t)t * B_ + b] = active ? 1.0f : 0.0f;
        if (active && !is_end) {
          #pragma unroll
          for (int j = 0; j < 8; ++j)
            if (tid + 64 * j == sel_i) { mreg[j] = 0.0f; ureg[j] = 1.0f; }
        }
        if (active && is_end) done_reg = 1;
      }
    } else {
      if (c + 1 < NCH) qprep(c + 1, (c + 1) & 1);
      if (c + 2 < NCH) gprep(c + 2, (c + 2) % 3);
    }
    bar_lds();
  }

  // wave0 publishes units
  if (tid < 64) {
    #pragma unroll
    for (int j = 0; j < 8; ++j) sm[OFF_UNITS + tid + 64 * j] = ureg[j];
    if (tid == 0) sm[OFF_UNITS + N_] = 0.f;
  }
  __syncthreads();

  // ======== epilogue: emb_sel & final ========
  {
    const int g = tid >> 5, cc = tid & 31;
    float p = 0.f;
    const int n0 = g * 32;
    for (int nn = 0; nn < 32; ++nn) {
      const int n = n0 + nn;
      p += sm[OFF_UNITS + n] * sm[OFF_KEY + cc * KROW + n];
    }
    if (g == 15) p += sm[OFF_UNITS + N_] * sm[OFF_KEY + cc * KROW + N_];
    sm[OFF_PART + g * 32 + cc] = p;
  }
  for (int n = tid; n < NP_; n += 512) out_units[(size_t)b * NP_ + n] = sm[OFF_UNITS + n];
  __syncthreads();
  if (tid < 32) {
    float s = 0.f;
    #pragma unroll
    for (int g = 0; g < 16; ++g) s += sm[OFF_PART + g * 32 + tid];
    sm[OFF_ES + tid] = s / 513.0f;
  }
  __syncthreads();
  {
    const float* e = emb + (size_t)b * 1024;
    for (int d = tid; d < 1024; d += 512) {
      float a = 0.f;
      #pragma unroll
      for (int k = 0; k < 32; ++k) a += sm[OFF_ES + k] * emb_w[k * 1024 + d];
      out_final[(size_t)b * 1024 + d] = e[d] + a + emb_b[d];
    }
  }
}

extern "C" void kernel_launch(void* const* d_in, const int* in_sizes, int n_in,
                              void* d_out, int out_size, void* d_ws, size_t ws_size,
                              hipStream_t stream) {
  (void)in_sizes; (void)n_in; (void)d_ws; (void)ws_size; (void)out_size;
  const float* emb    = (const float*)d_in[0];
  const float* autm   = (const float*)d_in[1];
  const float* aum    = (const float*)d_in[2];
  const float* ent    = (const float*)d_in[3];
  const float* temp   = (const float*)d_in[4];
  const float* key_w  = (const float*)d_in[5];
  const float* key_b  = (const float*)d_in[6];
  const float* func_w = (const float*)d_in[7];
  const float* func_b = (const float*)d_in[8];
  const float* fc1_w  = (const float*)d_in[9];
  const float* fc1_b  = (const float*)d_in[10];
  const float* fc2_w  = (const float*)d_in[11];
  const float* fc2_b  = (const float*)d_in[12];
  const float* emb_w  = (const float*)d_in[13];
  const float* emb_b  = (const float*)d_in[14];
  const float* wx     = (const float*)d_in[15];
  const float* wh     = (const float*)d_in[16];
  const float* lb     = (const float*)d_in[17];
  const float* gxg    = (const float*)d_in[18];
  const float* gxb    = (const float*)d_in[19];
  const float* ghg    = (const float*)d_in[20];
  const float* ghb    = (const float*)d_in[21];
  float* out = (float*)d_out;

  // output layout: logits[64,256,513] | valid[64,256] | units[256,513] | final[256,1024]
  const size_t OFF_V = (size_t)T_ * B_ * NP_;
  const size_t OFF_U = OFF_V + (size_t)T_ * B_;
  const size_t OFF_F = OFF_U + (size_t)B_ * NP_;

  SkKeys sk = compute_chain();

  suh_fused<<<dim3(B_), dim3(512), LDS_FLOATS * sizeof(float), stream>>>(
      emb, autm, aum, ent, temp, key_w, key_b, func_w, func_b,
      fc1_w, fc1_b, fc2_w, fc2_b, emb_w, emb_b,
      wx, wh, lb, gxg, gxb, ghg, ghb,
      out, out + OFF_V, out + OFF_U, out + OFF_F, sk);
}

// Round 11
// 250.908 us; speedup vs baseline: 1.5091x; 1.5091x over previous
//
#include <hip/hip_runtime.h>
#include <stdint.h>
#include <stddef.h>

// ==== JAX threefry mode: 1 = jax_threefry_partitionable (default in modern JAX)
#define JAX_PARTITIONABLE 1

#define B_   256
#define N_   512
#define NP_  513     // N+1
#define KROW 516     // padded key row stride (floats), 16B-aligned
#define T_   64
#define CS   4       // sampling chunk size (steps)
#define NCH  16      // T_/CS
#define NEGC 1e9f

// ---------------- threefry2x32 (matches jax/_src/prng.py) ----------------
__host__ __device__ __forceinline__ void tf2x32(uint32_t k0, uint32_t k1,
    uint32_t x0, uint32_t x1, uint32_t& o0, uint32_t& o1) {
  const uint32_t k2 = k0 ^ k1 ^ 0x1BD11BDAu;
#define TFR(r) { x0 += x1; x1 = (x1 << (r)) | (x1 >> (32 - (r))); x1 ^= x0; }
  x0 += k0; x1 += k1;
  TFR(13) TFR(15) TFR(26) TFR(6)
  x0 += k1; x1 += k2 + 1u;
  TFR(17) TFR(29) TFR(16) TFR(24)
  x0 += k2; x1 += k0 + 2u;
  TFR(13) TFR(15) TFR(26) TFR(6)
  x0 += k0; x1 += k1 + 3u;
  TFR(17) TFR(29) TFR(16) TFR(24)
  x0 += k1; x1 += k2 + 4u;
  TFR(13) TFR(15) TFR(26) TFR(6)
  x0 += k2; x1 += k0 + 5u;
#undef TFR
  o0 = x0; o1 = x1;
}

struct SkKeys { uint32_t k[128]; };

static SkKeys compute_chain() {
  SkKeys s;
  uint32_t r0 = 0u, r1 = 42u;   // jax.random.key(42)
  for (int t = 0; t < 64; ++t) {
#if JAX_PARTITIONABLE
    uint32_t a0, a1, b0, b1;
    tf2x32(r0, r1, 0u, 0u, a0, a1);
    tf2x32(r0, r1, 0u, 1u, b0, b1);
    s.k[2*t] = b0; s.k[2*t+1] = b1;
    r0 = a0; r1 = a1;
#else
    uint32_t p0, p1, q0, q1;
    tf2x32(r0, r1, 0u, 2u, p0, p1);
    tf2x32(r0, r1, 1u, 3u, q0, q1);
    s.k[2*t] = p1; s.k[2*t+1] = q1;
    r0 = p0; r1 = q0;
#endif
  }
  return s;
}

__device__ __forceinline__ float gumbel_draw(uint32_t k0, uint32_t k1, int b, int n) {
  uint32_t bits;
#if JAX_PARTITIONABLE
  uint32_t j = (uint32_t)(b * NP_ + n);
  uint32_t o0, o1; tf2x32(k0, k1, 0u, j, o0, o1);
  bits = o0 ^ o1;
#else
  int j = b * NP_ + n;
  uint32_t o0, o1;
  if (j < 65664) { tf2x32(k0, k1, (uint32_t)j, (uint32_t)(j + 65664), o0, o1); bits = o0; }
  else           { tf2x32(k0, k1, (uint32_t)(j - 65664), (uint32_t)j, o0, o1); bits = o1; }
#endif
  float f = __uint_as_float((bits >> 9) | 0x3F800000u) - 1.0f;
  const float TINY = 1.17549435e-38f;
  float u = fmaxf(TINY, f + TINY);
  return -logf(-logf(u));
}

__device__ __forceinline__ float sigm(float x) {
  return 0.5f + 0.5f * tanhf(0.5f * x);   // XLA logistic
}

// barrier with LDS-only drain (no vmcnt: global stores never read back)
__device__ __forceinline__ void bar_lds() {
  asm volatile("s_waitcnt lgkmcnt(0)\n\ts_barrier" ::: "memory");
}

// ---------------- LDS layout (floats) ----------------
#define OFF_KEY   0        // 32*516 = 16512, c-major [32][516]
#define OFF_H     16512    // 64*32 = 2048
#define OFF_Q     18560    // 2 slots * 4*516 = 4128
#define OFF_G     22688    // 5 slots * 4*516 = 10320
#define OFF_UNITS 33008    // 516
#define OFF_SK    33524    // 128 (u32 aliased)
#define OFF_ES    33652    // 32
#define OFF_PART  33684    // 512
#define OFF_T     34196    // 256
#define OFF_X0    34452    // 32
#define LDS_FLOATS 34484   // 137,936 B

__global__ void __launch_bounds__(512, 1)
suh_fused(const float* __restrict__ emb, const float* __restrict__ autm,
          const float* __restrict__ aum, const float* __restrict__ ent,
          const float* __restrict__ temp_p,
          const float* __restrict__ key_w, const float* __restrict__ key_b,
          const float* __restrict__ func_w, const float* __restrict__ func_b,
          const float* __restrict__ fc1_w, const float* __restrict__ fc1_b,
          const float* __restrict__ fc2_w, const float* __restrict__ fc2_b,
          const float* __restrict__ emb_w, const float* __restrict__ emb_b,
          const float* __restrict__ wx, const float* __restrict__ wh,
          const float* __restrict__ lstm_bb,
          const float* __restrict__ ln_gx, const float* __restrict__ ln_bx,
          const float* __restrict__ ln_gh, const float* __restrict__ ln_bh,
          float* __restrict__ out_logits, float* __restrict__ out_valid,
          float* __restrict__ out_units, float* __restrict__ out_final,
          SkKeys sk)
{
  extern __shared__ __align__(16) float sm[];
  int* smi = (int*)sm;
  const int b   = blockIdx.x;
  const int tid = threadIdx.x;
  const int L   = tid - 64;         // worker lane id (valid for tid >= 64)

  const float temp = temp_p[0];

  // ======== P0: T = relu(emb@fc1+b1) + relu(autm@func+fb) ========
  if (tid < 256) {
    float a = 0.f;
    const float* e = emb + (size_t)b * 1024;
    #pragma unroll 8
    for (int k = 0; k < 1024; ++k) a += e[k] * fc1_w[k * 256 + tid];
    a = fmaxf(a + fc1_b[tid], 0.f);
    float f = 0.f;
    const float* m = autm + (size_t)b * 259;
    for (int k = 0; k < 259; ++k) f += m[k] * func_w[k * 256 + tid];
    f = fmaxf(f + func_b[tid], 0.f);
    sm[OFF_T + tid] = a + f;
  } else {
    if (tid < 384) smi[OFF_SK + (tid - 256)] = (int)sk.k[tid - 256];
    if (tid >= 480) sm[OFF_KEY + (tid - 480) * KROW + N_] = 0.f;  // zero key row
  }
  __syncthreads();

  // ======== P1: x0 = relu(T@fc2 + b2) ========
  if (tid < 32) {
    float s = 0.f;
    #pragma unroll 8
    for (int m2 = 0; m2 < 256; ++m2) s += sm[OFF_T + m2] * fc2_w[m2 * 32 + tid];
    sm[OFF_X0 + tid] = fmaxf(s + fc2_b[tid], 0.f);
  }
  __syncthreads();

  // persistent worker state (key columns in registers)
  float kr0[32], kr1[32];
  // persistent wave0 sampling state
  float mreg[8], ureg[8];
  float m512 = 1.0f;
  int done_reg = 0;

  // prep lambdas (workers)
  auto qprep = [&](int cc, int qs) {
    const int qb = OFF_Q + qs * (CS * 516);
    #pragma unroll 1
    for (int tl = 0; tl < CS; ++tl) {
      const int hb = OFF_H + (cc * CS + tl) * 32;
      float hv[32];
      #pragma unroll
      for (int r = 0; r < 8; ++r) {
        float4 v = *(const float4*)&sm[hb + r * 4];
        hv[r*4] = v.x; hv[r*4+1] = v.y; hv[r*4+2] = v.z; hv[r*4+3] = v.w;
      }
      float a0 = 0.f;
      #pragma unroll
      for (int k = 0; k < 32; ++k) a0 += hv[k] * kr0[k];
      sm[qb + tl * 516 + L] = a0 * (1.0f / 32.0f);
      if (L < 64) {
        float a1 = 0.f;
        #pragma unroll
        for (int k = 0; k < 32; ++k) a1 += hv[k] * kr1[k];
        sm[qb + tl * 516 + L + 448] = a1 * (1.0f / 32.0f);
      }
    }
  };
  auto gprep = [&](int cc, int gs) {
    const int gb = OFF_G + gs * (CS * 516);
    #pragma unroll 1
    for (int i = 0; i < 5; ++i) {                 // ceil(CS*512/448)
      const int idx = i * 448 + L;
      if (idx < CS * 512) {
        const int tl = idx >> 9, n = idx & 511;
        const int t = cc * CS + tl;
        sm[gb + tl * 516 + n] =
            gumbel_draw((uint32_t)smi[OFF_SK + 2*t], (uint32_t)smi[OFF_SK + 2*t + 1], b, n);
      }
    }
    if (L < CS) {
      const int t = cc * CS + L;
      sm[gb + L * 516 + N_] =
          gumbel_draw((uint32_t)smi[OFF_SK + 2*t], (uint32_t)smi[OFF_SK + 2*t + 1], b, N_);
    }
  };

  // ======== P2: wave0 beta (64 LSTM steps) || workers key GEMM + gumbel prefill ========
  if (tid < 64) {
    // ---- persistent weights in VGPRs ----
    float wxr0[32], wxr1[32], whr0[32], whr1[32];
    #pragma unroll
    for (int k = 0; k < 32; ++k) {
      wxr0[k] = wx[k * 128 + tid];
      wxr1[k] = wx[k * 128 + 64 + tid];
      whr0[k] = wh[k * 128 + tid];
      whr1[k] = wh[k * 128 + 64 + tid];
    }
    const float gxg0 = ln_gx[tid], gxg1 = ln_gx[tid + 64];
    const float gxb0 = ln_bx[tid], gxb1 = ln_bx[tid + 64];
    const float ghg0 = ln_gh[tid], ghg1 = ln_gh[tid + 64];
    const float ghb0 = ln_bh[tid], ghb1 = ln_bh[tid + 64];
    const float lb0  = lstm_bb[tid], lb1 = lstm_bb[tid + 64];

    float xf[32];
    #pragma unroll
    for (int r = 0; r < 8; ++r) {
      float4 v = *(const float4*)&sm[OFF_X0 + r * 4];
      xf[r*4] = v.x; xf[r*4+1] = v.y; xf[r*4+2] = v.z; xf[r*4+3] = v.w;
    }
    float creg = 0.f;

    #pragma unroll 1
    for (int t = 0; t < T_; ++t) {
      // re-pin EVERY iteration: forbids rematerializing the weight loads
      // inside the loop (empty asm = zero instructions, pure reg constraint)
      #pragma unroll
      for (int k = 0; k < 32; ++k) {
        asm volatile("" : "+v"(wxr0[k]), "+v"(wxr1[k]), "+v"(whr0[k]), "+v"(whr1[k]));
      }
      float a0 = 0.f, a1 = 0.f, b0 = 0.f, b1 = 0.f;
      #pragma unroll
      for (int k = 0; k < 32; ++k) { a0 += xf[k] * wxr0[k]; a1 += xf[k] * wxr1[k]; }
      if (t > 0) {                        // at t==0, h==0 -> gh exactly 0
        #pragma unroll
        for (int k = 0; k < 32; ++k) { b0 += xf[k] * whr0[k]; b1 += xf[k] * whr1[k]; }
      }
      float sx = a0 + a1, sh = b0 + b1;
      for (int off = 32; off; off >>= 1) {
        sx += __shfl_down(sx, off);
        sh += __shfl_down(sh, off);
      }
      float mx  = __shfl(sx, 0) * (1.0f / 128.0f);
      float mh2 = __shfl(sh, 0) * (1.0f / 128.0f);
      float dx0 = a0 - mx, dx1 = a1 - mx;
      float dh0 = b0 - mh2, dh1 = b1 - mh2;
      float ssx = dx0 * dx0 + dx1 * dx1;
      float ssh = dh0 * dh0 + dh1 * dh1;
      for (int off = 32; off; off >>= 1) {
        ssx += __shfl_down(ssx, off);
        ssh += __shfl_down(ssh, off);
      }
      float vx = __shfl(ssx, 0) * (1.0f / 128.0f);
      float vh = __shfl(ssh, 0) * (1.0f / 128.0f);
      float rx = 1.0f / sqrtf(vx + 1e-5f);
      float rh = 1.0f / sqrtf(vh + 1e-5f);
      float lnx0 = dx0 * rx * gxg0 + gxb0;
      float lnx1 = dx1 * rx * gxg1 + gxb1;
      float lnh0 = dh0 * rh * ghg0 + ghb0;
      float lnh1 = dh1 * rh * ghg1 + ghb1;
      float g0 = lnx0 + lnh0 + lb0;       // gate[tid]     (i|f half)
      float g1 = lnx1 + lnh1 + lb1;       // gate[tid+64]  (o|u half)
      float fq = __shfl(g0, tid + 32);
      float uq = __shfl(g1, tid + 32);
      float cN = sigm(fq) * creg + sigm(g0) * tanhf(uq);
      float hN = sigm(g1) * tanhf(cN);
      creg = cN;                           // garbage in lanes>=32, never read
      if (tid < 32) sm[OFF_H + t * 32 + tid] = hN;
      #pragma unroll
      for (int k = 0; k < 32; ++k) xf[k] = __shfl(hN, k);   // h broadcast, no LDS read
    }
  } else {
    // ---- workers: key GEMM rows n = L (and L+448 for L<64), ascending-k chains ----
    const float4* kw4 = (const float4*)key_w;
    {
      const float4* er = (const float4*)(ent + ((size_t)b * N_ + L) * 256);
      float acc[32];
      #pragma unroll
      for (int c = 0; c < 32; ++c) acc[c] = 0.f;
      #pragma unroll 4
      for (int k4 = 0; k4 < 64; ++k4) {
        float4 ev = er[k4];
        float e4[4] = {ev.x, ev.y, ev.z, ev.w};
        #pragma unroll
        for (int j = 0; j < 4; ++j) {
          const int k = k4 * 4 + j;
          #pragma unroll
          for (int c4 = 0; c4 < 8; ++c4) {
            float4 w = kw4[k * 8 + c4];          // wave-uniform -> s_load
            acc[c4*4+0] += e4[j] * w.x;
            acc[c4*4+1] += e4[j] * w.y;
            acc[c4*4+2] += e4[j] * w.z;
            acc[c4*4+3] += e4[j] * w.w;
          }
        }
      }
      #pragma unroll
      for (int c = 0; c < 32; ++c) {
        kr0[c] = acc[c] + key_b[c];
        sm[OFF_KEY + c * KROW + L] = kr0[c];
      }
    }
    if (L < 64) {
      const int n = L + 448;
      const float4* er = (const float4*)(ent + ((size_t)b * N_ + n) * 256);
      float acc[32];
      #pragma unroll
      for (int c = 0; c < 32; ++c) acc[c] = 0.f;
      #pragma unroll 4
      for (int k4 = 0; k4 < 64; ++k4) {
        float4 ev = er[k4];
        float e4[4] = {ev.x, ev.y, ev.z, ev.w};
        #pragma unroll
        for (int j = 0; j < 4; ++j) {
          const int k = k4 * 4 + j;
          #pragma unroll
          for (int c4 = 0; c4 < 8; ++c4) {
            float4 w = kw4[k * 8 + c4];
            acc[c4*4+0] += e4[j] * w.x;
            acc[c4*4+1] += e4[j] * w.y;
            acc[c4*4+2] += e4[j] * w.z;
            acc[c4*4+3] += e4[j] * w.w;
          }
        }
      }
      #pragma unroll
      for (int c = 0; c < 32; ++c) {
        kr1[c] = acc[c] + key_b[c];
        sm[OFF_KEY + c * KROW + n] = kr1[c];
      }
    }
    #pragma unroll
    for (int k = 0; k < 32; ++k) {
      asm volatile("" : "+v"(kr0[k]), "+v"(kr1[k]));
    }
    // gumbel prefill for chunks 0..3 (G ring slots 0..3) — hidden under beta
    #pragma unroll 1
    for (int cc = 0; cc < 4; ++cc) gprep(cc, cc);
  }
  __syncthreads();   // H + key + G[0..3] complete

  // ======== P3 pre-loop: workers prep Q(0); wave0 loads mask state ========
  if (tid < 64) {
    #pragma unroll
    for (int j = 0; j < 8; ++j) {
      mreg[j] = aum[(size_t)b * N_ + tid + 64 * j];
      ureg[j] = 0.f;
    }
  } else {
    qprep(0, 0);
  }
  bar_lds();

  // ======== pipelined sampling: wave0 samples chunk c || workers prep Q(c+1), G(c+4) ========
  for (int c = 0; c < NCH; ++c) {
    if (tid < 64) {
      const int qbase = OFF_Q + (c & 1) * (CS * 516);
      const int gbase = OFF_G + (c % 5) * (CS * 516);
      #pragma unroll 1
      for (int tl = 0; tl < CS; ++tl) {
        const int t = c * CS + tl;
        float* lrow = out_logits + ((size_t)t * B_ + b) * NP_;
        float bv = 0.f; int bi = 0;
        #pragma unroll
        for (int j = 0; j < 8; ++j) {
          const int n = tid + 64 * j;
          float q = sm[qbase + tl * 516 + n] - (1.0f - mreg[j]) * NEGC;
          lrow[n] = q;
          float v = q / temp + sm[gbase + tl * 516 + n];
          if (j == 0) { bv = v; bi = n; }
          else if (v > bv) { bv = v; bi = n; }
        }
        if (tid == 0) {
          float q = -(1.0f - m512) * NEGC;   // zero key row: dot == 0
          lrow[N_] = q;
          float v = q / temp + sm[gbase + tl * 516 + N_];
          if (v > bv) { bv = v; bi = N_; }
        }
        for (int off = 32; off; off >>= 1) {
          float ov = __shfl_down(bv, off);
          int   oi = __shfl_down(bi, off);
          if (ov > bv || (ov == bv && oi < bi)) { bv = ov; bi = oi; }
        }
        const int sel_i = __shfl(bi, 0);
        const int active = !done_reg;
        const int is_end = (sel_i == N_);
        if (tid == 0) out_valid[(size_t)t * B_ + b] = active ? 1.0f : 0.0f;
        if (active && !is_end) {
          #pragma unroll
          for (int j = 0; j < 8; ++j)
            if (tid + 64 * j == sel_i) { mreg[j] = 0.0f; ureg[j] = 1.0f; }
        }
        if (active && is_end) done_reg = 1;
      }
    } else {
      if (c + 1 < NCH) qprep(c + 1, (c + 1) & 1);
      if (c + 4 < NCH) gprep(c + 4, (c + 4) % 5);
    }
    bar_lds();
  }

  // wave0 publishes units
  if (tid < 64) {
    #pragma unroll
    for (int j = 0; j < 8; ++j) sm[OFF_UNITS + tid + 64 * j] = ureg[j];
    if (tid == 0) sm[OFF_UNITS + N_] = 0.f;
  }
  __syncthreads();

  // ======== epilogue: emb_sel & final ========
  {
    const int g = tid >> 5, cc = tid & 31;
    float p = 0.f;
    const int n0 = g * 32;
    for (int nn = 0; nn < 32; ++nn) {
      const int n = n0 + nn;
      p += sm[OFF_UNITS + n] * sm[OFF_KEY + cc * KROW + n];
    }
    if (g == 15) p += sm[OFF_UNITS + N_] * sm[OFF_KEY + cc * KROW + N_];
    sm[OFF_PART + g * 32 + cc] = p;
  }
  for (int n = tid; n < NP_; n += 512) out_units[(size_t)b * NP_ + n] = sm[OFF_UNITS + n];
  __syncthreads();
  if (tid < 32) {
    float s = 0.f;
    #pragma unroll
    for (int g = 0; g < 16; ++g) s += sm[OFF_PART + g * 32 + tid];
    sm[OFF_ES + tid] = s / 513.0f;
  }
  __syncthreads();
  {
    const float* e = emb + (size_t)b * 1024;
    for (int d = tid; d < 1024; d += 512) {
      float a = 0.f;
      #pragma unroll
      for (int k = 0; k < 32; ++k) a += sm[OFF_ES + k] * emb_w[k * 1024 + d];
      out_final[(size_t)b * 1024 + d] = e[d] + a + emb_b[d];
    }
  }
}

extern "C" void kernel_launch(void* const* d_in, const int* in_sizes, int n_in,
                              void* d_out, int out_size, void* d_ws, size_t ws_size,
                              hipStream_t stream) {
  (void)in_sizes; (void)n_in; (void)d_ws; (void)ws_size; (void)out_size;
  const float* emb    = (const float*)d_in[0];
  const float* autm   = (const float*)d_in[1];
  const float* aum    = (const float*)d_in[2];
  const float* ent    = (const float*)d_in[3];
  const float* temp   = (const float*)d_in[4];
  const float* key_w  = (const float*)d_in[5];
  const float* key_b  = (const float*)d_in[6];
  const float* func_w = (const float*)d_in[7];
  const float* func_b = (const float*)d_in[8];
  const float* fc1_w  = (const float*)d_in[9];
  const float* fc1_b  = (const float*)d_in[10];
  const float* fc2_w  = (const float*)d_in[11];
  const float* fc2_b  = (const float*)d_in[12];
  const float* emb_w  = (const float*)d_in[13];
  const float* emb_b  = (const float*)d_in[14];
  const float* wx     = (const float*)d_in[15];
  const float* wh     = (const float*)d_in[16];
  const float* lb     = (const float*)d_in[17];
  const float* gxg    = (const float*)d_in[18];
  const float* gxb    = (const float*)d_in[19];
  const float* ghg    = (const float*)d_in[20];
  const float* ghb    = (const float*)d_in[21];
  float* out = (float*)d_out;

  // output layout: logits[64,256,513] | valid[64,256] | units[256,513] | final[256,1024]
  const size_t OFF_V = (size_t)T_ * B_ * NP_;
  const size_t OFF_U = OFF_V + (size_t)T_ * B_;
  const size_t OFF_F = OFF_U + (size_t)B_ * NP_;

  SkKeys sk = compute_chain();

  suh_fused<<<dim3(B_), dim3(512), LDS_FLOATS * sizeof(float), stream>>>(
      emb, autm, aum, ent, temp, key_w, key_b, func_w, func_b,
      fc1_w, fc1_b, fc2_w, fc2_b, emb_w, emb_b,
      wx, wh, lb, gxg, gxb, ghg, ghb,
      out, out + OFF_V, out + OFF_U, out + OFF_F, sk);
}

// Round 12
// 246.174 us; speedup vs baseline: 1.5381x; 1.0192x over previous
//
#include <hip/hip_runtime.h>
#include <stdint.h>
#include <stddef.h>

// ==== JAX threefry mode: 1 = jax_threefry_partitionable (default in modern JAX)
#define JAX_PARTITIONABLE 1

#define B_   256
#define N_   512
#define NP_  513     // N+1
#define KROW 516     // padded key row stride (floats), 16B-aligned
#define T_   64
#define CS   8       // sampling chunk size (steps)
#define NCH  8       // T_/CS
#define NEGC 1e9f

// ---------------- threefry2x32 (matches jax/_src/prng.py) ----------------
__host__ __device__ __forceinline__ void tf2x32(uint32_t k0, uint32_t k1,
    uint32_t x0, uint32_t x1, uint32_t& o0, uint32_t& o1) {
  const uint32_t k2 = k0 ^ k1 ^ 0x1BD11BDAu;
#define TFR(r) { x0 += x1; x1 = (x1 << (r)) | (x1 >> (32 - (r))); x1 ^= x0; }
  x0 += k0; x1 += k1;
  TFR(13) TFR(15) TFR(26) TFR(6)
  x0 += k1; x1 += k2 + 1u;
  TFR(17) TFR(29) TFR(16) TFR(24)
  x0 += k2; x1 += k0 + 2u;
  TFR(13) TFR(15) TFR(26) TFR(6)
  x0 += k0; x1 += k1 + 3u;
  TFR(17) TFR(29) TFR(16) TFR(24)
  x0 += k1; x1 += k2 + 4u;
  TFR(13) TFR(15) TFR(26) TFR(6)
  x0 += k2; x1 += k0 + 5u;
#undef TFR
  o0 = x0; o1 = x1;
}

struct SkKeys { uint32_t k[128]; };

static SkKeys compute_chain() {
  SkKeys s;
  uint32_t r0 = 0u, r1 = 42u;   // jax.random.key(42)
  for (int t = 0; t < 64; ++t) {
#if JAX_PARTITIONABLE
    uint32_t a0, a1, b0, b1;
    tf2x32(r0, r1, 0u, 0u, a0, a1);
    tf2x32(r0, r1, 0u, 1u, b0, b1);
    s.k[2*t] = b0; s.k[2*t+1] = b1;
    r0 = a0; r1 = a1;
#else
    uint32_t p0, p1, q0, q1;
    tf2x32(r0, r1, 0u, 2u, p0, p1);
    tf2x32(r0, r1, 1u, 3u, q0, q1);
    s.k[2*t] = p1; s.k[2*t+1] = q1;
    r0 = p0; r1 = q0;
#endif
  }
  return s;
}

__device__ __forceinline__ float gumbel_draw(uint32_t k0, uint32_t k1, int b, int n) {
  uint32_t bits;
#if JAX_PARTITIONABLE
  uint32_t j = (uint32_t)(b * NP_ + n);
  uint32_t o0, o1; tf2x32(k0, k1, 0u, j, o0, o1);
  bits = o0 ^ o1;
#else
  int j = b * NP_ + n;
  uint32_t o0, o1;
  if (j < 65664) { tf2x32(k0, k1, (uint32_t)j, (uint32_t)(j + 65664), o0, o1); bits = o0; }
  else           { tf2x32(k0, k1, (uint32_t)(j - 65664), (uint32_t)j, o0, o1); bits = o1; }
#endif
  float f = __uint_as_float((bits >> 9) | 0x3F800000u) - 1.0f;
  const float TINY = 1.17549435e-38f;
  float u = fmaxf(TINY, f + TINY);
  return -logf(-logf(u));
}

__device__ __forceinline__ float sigm(float x) {
  return 0.5f + 0.5f * tanhf(0.5f * x);   // XLA logistic
}

// barrier with LDS-only drain (no vmcnt: global stores never read back)
__device__ __forceinline__ void bar_lds() {
  asm volatile("s_waitcnt lgkmcnt(0)\n\ts_barrier" ::: "memory");
}

// ---------------- LDS layout (floats) ----------------
#define OFF_KEY   0        // 32*516 = 16512, c-major [32][516]
#define OFF_H     16512    // 64*32 = 2048
#define OFF_Q     18560    // 2 slots * 8*516 = 8256
#define OFF_G     26816    // 2 slots * 8*516 = 8256
#define OFF_UNITS 35072    // 516
#define OFF_SK    35588    // 128 (u32 aliased)
#define OFF_ES    35716    // 32
#define OFF_PART  35748    // 512
#define OFF_T     36260    // 256
#define OFF_X0    36516    // 32
#define LDS_FLOATS 36548   // 146,192 B

__global__ void __launch_bounds__(512, 1)
suh_fused(const float* __restrict__ emb, const float* __restrict__ autm,
          const float* __restrict__ aum, const float* __restrict__ ent,
          const float* __restrict__ temp_p,
          const float* __restrict__ key_w, const float* __restrict__ key_b,
          const float* __restrict__ func_w, const float* __restrict__ func_b,
          const float* __restrict__ fc1_w, const float* __restrict__ fc1_b,
          const float* __restrict__ fc2_w, const float* __restrict__ fc2_b,
          const float* __restrict__ emb_w, const float* __restrict__ emb_b,
          const float* __restrict__ wx, const float* __restrict__ wh,
          const float* __restrict__ lstm_bb,
          const float* __restrict__ ln_gx, const float* __restrict__ ln_bx,
          const float* __restrict__ ln_gh, const float* __restrict__ ln_bh,
          float* __restrict__ out_logits, float* __restrict__ out_valid,
          float* __restrict__ out_units, float* __restrict__ out_final,
          SkKeys sk)
{
  extern __shared__ __align__(16) float sm[];
  int* smi = (int*)sm;
  const int b   = blockIdx.x;
  const int tid = threadIdx.x;
  const int L   = tid - 64;         // worker lane id (valid for tid >= 64)

  const float temp = temp_p[0];

  // ======== P0: T = relu(emb@fc1+b1) + relu(autm@func+fb) ========
  if (tid < 256) {
    float a = 0.f;
    const float* e = emb + (size_t)b * 1024;
    #pragma unroll 8
    for (int k = 0; k < 1024; ++k) a += e[k] * fc1_w[k * 256 + tid];
    a = fmaxf(a + fc1_b[tid], 0.f);
    float f = 0.f;
    const float* m = autm + (size_t)b * 259;
    for (int k = 0; k < 259; ++k) f += m[k] * func_w[k * 256 + tid];
    f = fmaxf(f + func_b[tid], 0.f);
    sm[OFF_T + tid] = a + f;
  } else {
    if (tid < 384) smi[OFF_SK + (tid - 256)] = (int)sk.k[tid - 256];
    if (tid >= 480) sm[OFF_KEY + (tid - 480) * KROW + N_] = 0.f;  // zero key row
  }
  __syncthreads();

  // ======== P1: x0 = relu(T@fc2 + b2) ========
  if (tid < 32) {
    float s = 0.f;
    #pragma unroll 8
    for (int m2 = 0; m2 < 256; ++m2) s += sm[OFF_T + m2] * fc2_w[m2 * 32 + tid];
    sm[OFF_X0 + tid] = fmaxf(s + fc2_b[tid], 0.f);
  }
  __syncthreads();

  // persistent worker state (key columns in registers)
  float kr0[32], kr1[32];
  // persistent wave0 sampling state
  float mreg[8], ureg[8];
  float m512 = 1.0f;
  int done_reg = 0;

  // prep lambdas (workers, L = 0..447)
  auto qprep = [&](int cc, int qs) {
    const int qb = OFF_Q + qs * (CS * 516);
    #pragma unroll 1
    for (int tl = 0; tl < CS; ++tl) {
      const int hb = OFF_H + (cc * CS + tl) * 32;
      float hv[32];
      #pragma unroll
      for (int r = 0; r < 8; ++r) {
        float4 v = *(const float4*)&sm[hb + r * 4];
        hv[r*4] = v.x; hv[r*4+1] = v.y; hv[r*4+2] = v.z; hv[r*4+3] = v.w;
      }
      float a0 = 0.f;
      #pragma unroll
      for (int k = 0; k < 32; ++k) a0 += hv[k] * kr0[k];
      sm[qb + tl * 516 + L] = a0 * (1.0f / 32.0f);
      if (L < 64) {
        float a1 = 0.f;
        #pragma unroll
        for (int k = 0; k < 32; ++k) a1 += hv[k] * kr1[k];
        sm[qb + tl * 516 + L + 448] = a1 * (1.0f / 32.0f);
      }
    }
  };
  auto gprep = [&](int cc, int gs) {
    const int gb = OFF_G + gs * (CS * 516);
    #pragma unroll 1
    for (int i = 0; i < 10; ++i) {                // ceil(CS*512/448)
      const int idx = i * 448 + L;
      if (idx < CS * 512) {
        const int tl = idx >> 9, n = idx & 511;
        const int t = cc * CS + tl;
        sm[gb + tl * 516 + n] =
            gumbel_draw((uint32_t)smi[OFF_SK + 2*t], (uint32_t)smi[OFF_SK + 2*t + 1], b, n);
      }
    }
    if (L < CS) {
      const int t = cc * CS + L;
      sm[gb + L * 516 + N_] =
          gumbel_draw((uint32_t)smi[OFF_SK + 2*t], (uint32_t)smi[OFF_SK + 2*t + 1], b, N_);
    }
  };

  // ======== P2: wave0 beta (64 LSTM steps) || workers key GEMM + gumbel prefill ========
  if (tid < 64) {
    // ---- weights loaded once, then LAUNDERED through a volatile mov:
    // the loop consumes the asm's result, which cannot be rematerialized ----
    float wxr0[32], wxr1[32], whr0[32], whr1[32];
    #pragma unroll
    for (int k = 0; k < 32; ++k) {
      wxr0[k] = wx[k * 128 + tid];
      wxr1[k] = wx[k * 128 + 64 + tid];
      whr0[k] = wh[k * 128 + tid];
      whr1[k] = wh[k * 128 + 64 + tid];
    }
    #pragma unroll
    for (int k = 0; k < 32; ++k) {
      asm volatile("v_mov_b32 %0, %0" : "+v"(wxr0[k]));
      asm volatile("v_mov_b32 %0, %0" : "+v"(wxr1[k]));
      asm volatile("v_mov_b32 %0, %0" : "+v"(whr0[k]));
      asm volatile("v_mov_b32 %0, %0" : "+v"(whr1[k]));
    }
    const float gxg0 = ln_gx[tid], gxg1 = ln_gx[tid + 64];
    const float gxb0 = ln_bx[tid], gxb1 = ln_bx[tid + 64];
    const float ghg0 = ln_gh[tid], ghg1 = ln_gh[tid + 64];
    const float ghb0 = ln_bh[tid], ghb1 = ln_bh[tid + 64];
    const float lb0  = lstm_bb[tid], lb1 = lstm_bb[tid + 64];

    float xf[32];
    #pragma unroll
    for (int r = 0; r < 8; ++r) {
      float4 v = *(const float4*)&sm[OFF_X0 + r * 4];
      xf[r*4] = v.x; xf[r*4+1] = v.y; xf[r*4+2] = v.z; xf[r*4+3] = v.w;
    }
    float creg = 0.f;

    #pragma unroll 1
    for (int t = 0; t < T_; ++t) {
      float a0 = 0.f, a1 = 0.f, b0 = 0.f, b1 = 0.f;
      #pragma unroll
      for (int k = 0; k < 32; ++k) { a0 += xf[k] * wxr0[k]; a1 += xf[k] * wxr1[k]; }
      if (t > 0) {                        // at t==0, h==0 -> gh exactly 0
        #pragma unroll
        for (int k = 0; k < 32; ++k) { b0 += xf[k] * whr0[k]; b1 += xf[k] * whr1[k]; }
      }
      // xor-butterfly: every lane gets the bit-identical full sum (fp add is
      // commutative; tree shape identical to the old shfl_down+broadcast)
      float sx = a0 + a1, sh = b0 + b1;
      for (int off = 32; off; off >>= 1) {
        sx += __shfl_xor(sx, off);
        sh += __shfl_xor(sh, off);
      }
      float mx  = sx * (1.0f / 128.0f);
      float mh2 = sh * (1.0f / 128.0f);
      float dx0 = a0 - mx, dx1 = a1 - mx;
      float dh0 = b0 - mh2, dh1 = b1 - mh2;
      float ssx = dx0 * dx0 + dx1 * dx1;
      float ssh = dh0 * dh0 + dh1 * dh1;
      for (int off = 32; off; off >>= 1) {
        ssx += __shfl_xor(ssx, off);
        ssh += __shfl_xor(ssh, off);
      }
      float vx = ssx * (1.0f / 128.0f);
      float vh = ssh * (1.0f / 128.0f);
      float rx = 1.0f / sqrtf(vx + 1e-5f);
      float rh = 1.0f / sqrtf(vh + 1e-5f);
      float lnx0 = dx0 * rx * gxg0 + gxb0;
      float lnx1 = dx1 * rx * gxg1 + gxb1;
      float lnh0 = dh0 * rh * ghg0 + ghb0;
      float lnh1 = dh1 * rh * ghg1 + ghb1;
      float g0 = lnx0 + lnh0 + lb0;       // gate[tid]     (i|f half)
      float g1 = lnx1 + lnh1 + lb1;       // gate[tid+64]  (o|u half)
      float fq = __shfl(g0, tid + 32);
      float uq = __shfl(g1, tid + 32);
      float cN = sigm(fq) * creg + sigm(g0) * tanhf(uq);
      float hN = sigm(g1) * tanhf(cN);
      creg = cN;                           // garbage in lanes>=32, never read
      if (tid < 32) sm[OFF_H + t * 32 + tid] = hN;
      #pragma unroll
      for (int k = 0; k < 32; ++k) xf[k] = __shfl(hN, k);   // h broadcast
    }
  } else {
    // ---- workers: key GEMM rows n = L (and L+448 for L<64), ascending-k chains ----
    const float4* kw4 = (const float4*)key_w;
    {
      const float4* er = (const float4*)(ent + ((size_t)b * N_ + L) * 256);
      float acc[32];
      #pragma unroll
      for (int c = 0; c < 32; ++c) acc[c] = 0.f;
      #pragma unroll 4
      for (int k4 = 0; k4 < 64; ++k4) {
        float4 ev = er[k4];
        float e4[4] = {ev.x, ev.y, ev.z, ev.w};
        #pragma unroll
        for (int j = 0; j < 4; ++j) {
          const int k = k4 * 4 + j;
          #pragma unroll
          for (int c4 = 0; c4 < 8; ++c4) {
            float4 w = kw4[k * 8 + c4];          // wave-uniform -> s_load
            acc[c4*4+0] += e4[j] * w.x;
            acc[c4*4+1] += e4[j] * w.y;
            acc[c4*4+2] += e4[j] * w.z;
            acc[c4*4+3] += e4[j] * w.w;
          }
        }
      }
      #pragma unroll
      for (int c = 0; c < 32; ++c) {
        kr0[c] = acc[c] + key_b[c];
        sm[OFF_KEY + c * KROW + L] = kr0[c];
      }
    }
    if (L < 64) {
      const int n = L + 448;
      const float4* er = (const float4*)(ent + ((size_t)b * N_ + n) * 256);
      float acc[32];
      #pragma unroll
      for (int c = 0; c < 32; ++c) acc[c] = 0.f;
      #pragma unroll 4
      for (int k4 = 0; k4 < 64; ++k4) {
        float4 ev = er[k4];
        float e4[4] = {ev.x, ev.y, ev.z, ev.w};
        #pragma unroll
        for (int j = 0; j < 4; ++j) {
          const int k = k4 * 4 + j;
          #pragma unroll
          for (int c4 = 0; c4 < 8; ++c4) {
            float4 w = kw4[k * 8 + c4];
            acc[c4*4+0] += e4[j] * w.x;
            acc[c4*4+1] += e4[j] * w.y;
            acc[c4*4+2] += e4[j] * w.z;
            acc[c4*4+3] += e4[j] * w.w;
          }
        }
      }
      #pragma unroll
      for (int c = 0; c < 32; ++c) {
        kr1[c] = acc[c] + key_b[c];
        sm[OFF_KEY + c * KROW + n] = kr1[c];
      }
    }
    #pragma unroll
    for (int k = 0; k < 32; ++k) {
      asm volatile("" : "+v"(kr0[k]), "+v"(kr1[k]));
    }
    // gumbel prefill for chunk 0 (G ring slot 0) — hidden under beta
    gprep(0, 0);
  }
  __syncthreads();   // H + key + G[0] complete

  // ======== P3 pre-loop: workers prep Q(0); wave0 loads mask state ========
  if (tid < 64) {
    #pragma unroll
    for (int j = 0; j < 8; ++j) {
      mreg[j] = aum[(size_t)b * N_ + tid + 64 * j];
      ureg[j] = 0.f;
    }
  } else {
    qprep(0, 0);
  }
  bar_lds();

  // ======== pipelined sampling: wave0 samples chunk c || workers prep Q(c+1), G(c+1) ========
  for (int c = 0; c < NCH; ++c) {
    if (tid < 64) {
      const int qbase = OFF_Q + (c & 1) * (CS * 516);
      const int gbase = OFF_G + (c & 1) * (CS * 516);
      #pragma unroll 1
      for (int tl = 0; tl < CS; ++tl) {
        const int t = c * CS + tl;
        float* lrow = out_logits + ((size_t)t * B_ + b) * NP_;
        float bv = 0.f; int bi = 0;
        #pragma unroll
        for (int j = 0; j < 8; ++j) {
          const int n = tid + 64 * j;
          float q = sm[qbase + tl * 516 + n] - (1.0f - mreg[j]) * NEGC;
          lrow[n] = q;
          float v = q / temp + sm[gbase + tl * 516 + n];
          if (j == 0) { bv = v; bi = n; }
          else if (v > bv) { bv = v; bi = n; }
        }
        if (tid == 0) {
          float q = -(1.0f - m512) * NEGC;   // zero key row: dot == 0
          lrow[N_] = q;
          float v = q / temp + sm[gbase + tl * 516 + N_];
          if (v > bv) { bv = v; bi = N_; }
        }
        for (int off = 32; off; off >>= 1) {
          float ov = __shfl_down(bv, off);
          int   oi = __shfl_down(bi, off);
          if (ov > bv || (ov == bv && oi < bi)) { bv = ov; bi = oi; }
        }
        const int sel_i = __shfl(bi, 0);
        const int active = !done_reg;
        const int is_end = (sel_i == N_);
        if (tid == 0) out_valid[(size_t)t * B_ + b] = active ? 1.0f : 0.0f;
        if (active && !is_end) {
          #pragma unroll
          for (int j = 0; j < 8; ++j)
            if (tid + 64 * j == sel_i) { mreg[j] = 0.0f; ureg[j] = 1.0f; }
        }
        if (active && is_end) done_reg = 1;
      }
    } else {
      if (c + 1 < NCH) {
        qprep(c + 1, (c + 1) & 1);
        gprep(c + 1, (c + 1) & 1);
      }
    }
    bar_lds();
  }

  // wave0 publishes units
  if (tid < 64) {
    #pragma unroll
    for (int j = 0; j < 8; ++j) sm[OFF_UNITS + tid + 64 * j] = ureg[j];
    if (tid == 0) sm[OFF_UNITS + N_] = 0.f;
  }
  __syncthreads();

  // ======== epilogue: emb_sel & final ========
  {
    const int g = tid >> 5, cc = tid & 31;
    float p = 0.f;
    const int n0 = g * 32;
    for (int nn = 0; nn < 32; ++nn) {
      const int n = n0 + nn;
      p += sm[OFF_UNITS + n] * sm[OFF_KEY + cc * KROW + n];
    }
    if (g == 15) p += sm[OFF_UNITS + N_] * sm[OFF_KEY + cc * KROW + N_];
    sm[OFF_PART + g * 32 + cc] = p;
  }
  for (int n = tid; n < NP_; n += 512) out_units[(size_t)b * NP_ + n] = sm[OFF_UNITS + n];
  __syncthreads();
  if (tid < 32) {
    float s = 0.f;
    #pragma unroll
    for (int g = 0; g < 16; ++g) s += sm[OFF_PART + g * 32 + tid];
    sm[OFF_ES + tid] = s / 513.0f;
  }
  __syncthreads();
  {
    const float* e = emb + (size_t)b * 1024;
    for (int d = tid; d < 1024; d += 512) {
      float a = 0.f;
      #pragma unroll
      for (int k = 0; k < 32; ++k) a += sm[OFF_ES + k] * emb_w[k * 1024 + d];
      out_final[(size_t)b * 1024 + d] = e[d] + a + emb_b[d];
    }
  }
}

extern "C" void kernel_launch(void* const* d_in, const int* in_sizes, int n_in,
                              void* d_out, int out_size, void* d_ws, size_t ws_size,
                              hipStream_t stream) {
  (void)in_sizes; (void)n_in; (void)d_ws; (void)ws_size; (void)out_size;
  const float* emb    = (const float*)d_in[0];
  const float* autm   = (const float*)d_in[1];
  const float* aum    = (const float*)d_in[2];
  const float* ent    = (const float*)d_in[3];
  const float* temp   = (const float*)d_in[4];
  const float* key_w  = (const float*)d_in[5];
  const float* key_b  = (const float*)d_in[6];
  const float* func_w = (const float*)d_in[7];
  const float* func_b = (const float*)d_in[8];
  const float* fc1_w  = (const float*)d_in[9];
  const float* fc1_b  = (const float*)d_in[10];
  const float* fc2_w  = (const float*)d_in[11];
  const float* fc2_b  = (const float*)d_in[12];
  const float* emb_w  = (const float*)d_in[13];
  const float* emb_b  = (const float*)d_in[14];
  const float* wx     = (const float*)d_in[15];
  const float* wh     = (const float*)d_in[16];
  const float* lb     = (const float*)d_in[17];
  const float* gxg    = (const float*)d_in[18];
  const float* gxb    = (const float*)d_in[19];
  const float* ghg    = (const float*)d_in[20];
  const float* ghb    = (const float*)d_in[21];
  float* out = (float*)d_out;

  // output layout: logits[64,256,513] | valid[64,256] | units[256,513] | final[256,1024]
  const size_t OFF_V = (size_t)T_ * B_ * NP_;
  const size_t OFF_U = OFF_V + (size_t)T_ * B_;
  const size_t OFF_F = OFF_U + (size_t)B_ * NP_;

  SkKeys sk = compute_chain();

  suh_fused<<<dim3(B_), dim3(512), LDS_FLOATS * sizeof(float), stream>>>(
      emb, autm, aum, ent, temp, key_w, key_b, func_w, func_b,
      fc1_w, fc1_b, fc2_w, fc2_b, emb_w, emb_b,
      wx, wh, lb, gxg, gxb, ghg, ghb,
      out, out + OFF_V, out + OFF_U, out + OFF_F, sk);
}